// Round 7
// baseline (71.103 us; speedup 1.0000x reference)
//
#include <hip/hip_runtime.h>
#include <hip/hip_bf16.h>
#include <math.h>

typedef unsigned short u16;
typedef unsigned int   u32;
typedef __attribute__((ext_vector_type(8))) short short8;
typedef __attribute__((ext_vector_type(4))) float f32x4;

// Problem constants
#define B_  4
#define C_  64
#define H_  128
#define W_  128
#define O_  64
#define HW_ (H_ * W_)

__device__ __forceinline__ u16 f2bf(float f) {
    __hip_bfloat16 h = __float2bfloat16(f);
    u16 u; __builtin_memcpy(&u, &h, 2); return u;
}
// pack two f32 -> [hi|lo] bf16 pair, hardware RNE (no builtin on gfx950)
__device__ __forceinline__ u32 cvt_pk_bf16(float lo, float hi) {
    u32 r; asm("v_cvt_pk_bf16_f32 %0, %1, %2" : "=v"(r) : "v"(lo), "v"(hi));
    return r;
}
__device__ __forceinline__ float bflo(u32 v) { return __uint_as_float(v << 16); }
__device__ __forceinline__ float bfhi(u32 v) { return __uint_as_float(v & 0xffff0000u); }

// -------------------------------------------------------------------------
// repack: Wb  (4 otile,18 ks,64 lane,8 j) bf16  from weight (O,C,3,3)
//         OWb (2 otile,18 ks,64 lane,8 j) bf16  from ow|mw|0
// K index convention: kidx = tap*64 + c  (tap-major, channel minor)
// A-frag (16x16x32): lane l holds A[o = l&15][k = ks*32 + (l>>4)*8 + j]
// -------------------------------------------------------------------------
__global__ __launch_bounds__(256) void repack(
    const float* __restrict__ weight,
    const float* __restrict__ ow, const float* __restrict__ mw,
    u16* __restrict__ Wb, u16* __restrict__ OWb)
{
    int t = blockIdx.x * 256 + threadIdx.x;      // 216 blocks = 55296 threads
    if (t < 36864) {                             // Wb
        int e = t;
        int j = e & 7, ln = (e >> 3) & 63;
        int ks = (e >> 9) % 18, ot = e / 9216;
        int o = ot * 16 + (ln & 15);
        int kidx = ks * 32 + ((ln >> 4) << 3) + j;
        int k = kidx >> 6, c = kidx & 63;
        Wb[e] = f2bf(weight[((size_t)(o * 64 + c)) * 9 + k]);
    } else {                                     // OWb
        int e = t - 36864;
        int j = e & 7, ln = (e >> 3) & 63;
        int ks = (e >> 9) % 18, ot = e / 9216;
        int o = ot * 16 + (ln & 15);
        int kidx = ks * 32 + ((ln >> 4) << 3) + j;
        int k = kidx >> 6, c = kidx & 63;
        float v = 0.0f;
        if (o < 18)      v = ow[((size_t)(o * 64 + c)) * 9 + k];
        else if (o < 27) v = mw[((size_t)((o - 18) * 64 + c)) * 9 + k];
        OWb[e] = f2bf(v);
    }
}

// -------------------------------------------------------------------------
// prep_t: transpose all 4 batches of x (B,C,H,W) f32 -> xt (B,H,W,C) bf16
// -------------------------------------------------------------------------
__global__ __launch_bounds__(256) void prep_t(
    const float* __restrict__ x, u16* __restrict__ xt)
{
    __shared__ float tile[64][65];
    int i = blockIdx.x, t = threadIdx.x;        // 1024 blocks
    int lb = i >> 8;                            // 0..3
    int pix0 = (i & 255) << 6;
    const float* xb = x + ((size_t)lb << 20);   // lb * C*HW
#pragma unroll
    for (int it = 0; it < 16; ++it) {
        int e = it * 256 + t;
        int c = e >> 6, pl = e & 63;
        tile[c][pl] = xb[((size_t)c << 14) + pix0 + pl];
    }
    __syncthreads();
    u16* xo = xt + ((((size_t)lb << 14) + pix0) << 6);
#pragma unroll
    for (int it = 0; it < 16; ++it) {
        int e = it * 256 + t;
        int c = e & 63, pl = e >> 6;
        xo[((size_t)pl << 6) + c] = f2bf(tile[c][pl]);
    }
}

// -------------------------------------------------------------------------
// fused_dcn: WAVE-AUTONOMOUS. Each wave owns 16 pixels (one row segment):
//   K1  : 27-ch offset/mask conv, B-frags loaded DIRECT from global xt
//         (regular im2col, cndmask zero-padding), both o-tiles in-wave.
//   st1 : bilinear corner byte-offsets (int4) + f32 weights -> per-wave LDS
//   K2  : per tap: gather 4 corners x 8ch/lane (dwordx4), interpolate in
//         f32, cvt_pk -> B-frag IN REGISTERS (lane = (ch-octet, pixel)
//         matches B layout), 4 o-tile MFMAs. acc[4] = all 64 outputs.
// No __syncthreads anywhere; LDS is per-wave handoff only (12.7 KB/block).
// -------------------------------------------------------------------------
__global__ __launch_bounds__(128, 4) void fused_dcn(
    const u16* __restrict__ xt,
    const u16* __restrict__ Wb, const u16* __restrict__ OWb,
    const float* __restrict__ ob, const float* __restrict__ mb,
    float* __restrict__ out)
{
    __shared__ float  param[2][27][16];   // 3456 B
    __shared__ int4   pwp[2][144];        // 9216 B total with pww
    __shared__ float4 pww[2][144];

    const int t = threadIdx.x;
    const int lane = t & 63;
    const int wv = t >> 6;          // 0..1
    const int mypix = lane & 15;
    const int hi = lane >> 4;       // channel octet index

    int bid0 = blockIdx.x;          // 2048 blocks
    const int bid = (bid0 & 7) * 256 + (bid0 >> 3);   // XCD swizzle (bijective)
    const int task = bid * 2 + wv;  // 0..4095 wave task
    const int lb = task >> 10;      // batch
    const int pix0 = (task & 1023) << 4;
    const int h  = pix0 >> 7;       // 16 pixels share one row
    const int w0 = pix0 & 127;

    const u16* xtb = xt + ((size_t)lb << 20);

    // ---- K1: offset/mask conv, direct global im2col B-frags ----
    f32x4 k1a = {0.f, 0.f, 0.f, 0.f};
    f32x4 k1b = {0.f, 0.f, 0.f, 0.f};
#pragma unroll
    for (int ks = 0; ks < 18; ++ks) {
        const int tap = ks >> 1;
        const int ky = tap / 3, kx = tap % 3;
        int y  = h - 1 + ky;
        int xx = w0 + mypix - 1 + kx;
        bool valid = ((unsigned)y < (unsigned)H_) && ((unsigned)xx < (unsigned)W_);
        int idx = (((y & 127) << 7) + (xx & 127));    // wrapped -> safe address
        uint4 raw = *(const uint4*)(xtb + ((size_t)idx << 6) + ((ks & 1) << 5) + (hi << 3));
        raw.x = valid ? raw.x : 0u;
        raw.y = valid ? raw.y : 0u;
        raw.z = valid ? raw.z : 0u;
        raw.w = valid ? raw.w : 0u;
        short8 bfr;
        __builtin_memcpy(&bfr, &raw, 16);
        short8 wa0 = ((const short8*)OWb)[(0 * 18 + ks) * 64 + lane];
        short8 wa1 = ((const short8*)OWb)[(1 * 18 + ks) * 64 + lane];
        k1a = __builtin_amdgcn_mfma_f32_16x16x32_bf16(wa0, bfr, k1a, 0, 0, 0);
        k1b = __builtin_amdgcn_mfma_f32_16x16x32_bf16(wa1, bfr, k1b, 0, 0, 0);
    }
    // D-frag -> param[oc][pix]  (oc = otile*16 + hi*4 + r)
#pragma unroll
    for (int r = 0; r < 4; ++r) {
        int oc0 = (hi << 2) + r;          // 0..15 : offsets
        param[wv][oc0][mypix] = k1a[r] + ob[oc0];
        int oc1 = 16 + (hi << 2) + r;     // 16..31
        if (oc1 < 18) {
            param[wv][oc1][mypix] = k1b[r] + ob[oc1];
        } else if (oc1 < 27) {
            float s = k1b[r] + mb[oc1 - 18];
            param[wv][oc1][mypix] = 2.0f / (1.0f + __expf(-s));
        }
    }

    // ---- step 1: bilinear corner offsets + weights (per-wave, no barrier) ----
#pragma unroll
    for (int it = 0; it < 3; ++it) {
        int p = it * 64 + lane;
        if (p < 144) {
            int tap = p >> 4, pixl = p & 15;
            int ky = tap / 3, kx = tap % 3;
            float dy = param[wv][2 * tap][pixl];
            float dx = param[wv][2 * tap + 1][pixl];
            float m  = param[wv][18 + tap][pixl];
            float py = (float)(h - 1 + ky) + dy;
            float px = (float)(w0 + pixl - 1 + kx) + dx;
            float y0f = floorf(py), x0f = floorf(px);
            float fy = py - y0f, fx = px - x0f;
            int y0 = (int)y0f, x0 = (int)x0f;
            int y1 = y0 + 1, x1 = x0 + 1;
            bool vy0 = (unsigned)y0 < (unsigned)H_;
            bool vy1 = (unsigned)y1 < (unsigned)H_;
            bool vx0 = (unsigned)x0 < (unsigned)W_;
            bool vx1 = (unsigned)x1 < (unsigned)W_;
            float w00 = (1.f - fy) * (1.f - fx) * m; if (!(vy0 && vx0)) w00 = 0.f;
            float w01 = (1.f - fy) * fx          * m; if (!(vy0 && vx1)) w01 = 0.f;
            float w10 = fy * (1.f - fx)          * m; if (!(vy1 && vx0)) w10 = 0.f;
            float w11 = fy * fx                   * m; if (!(vy1 && vx1)) w11 = 0.f;
            int y0c = min(max(y0, 0), H_ - 1);
            int y1c = min(max(y1, 0), H_ - 1);
            int x0c = min(max(x0, 0), W_ - 1);
            int x1c = min(max(x1, 0), W_ - 1);
            // byte offsets into xt batch slab: (pos<<6 elems)<<1 = pos<<7
            pwp[wv][p] = make_int4(((y0c << 7) + x0c) << 7, ((y0c << 7) + x1c) << 7,
                                   ((y1c << 7) + x0c) << 7, ((y1c << 7) + x1c) << 7);
            pww[wv][p] = make_float4(w00, w01, w10, w11);
        }
    }

    // ---- K2: gather + in-register B-frag + 4 o-tile MFMAs ----
    f32x4 acc0 = {0.f,0.f,0.f,0.f}, acc1 = {0.f,0.f,0.f,0.f};
    f32x4 acc2 = {0.f,0.f,0.f,0.f}, acc3 = {0.f,0.f,0.f,0.f};
    const char* xb8 = (const char*)xtb;
    const int coff0 = hi << 4;            // byte offset of channel octet
#pragma unroll 1
    for (int tap = 0; tap < 9; ++tap) {
        int4   ofs = pwp[wv][(tap << 4) + mypix];
        float4 wt  = pww[wv][(tap << 4) + mypix];
#pragma unroll
        for (int k2 = 0; k2 < 2; ++k2) {
            int co = coff0 + (k2 << 6);
            uint4 r00 = *(const uint4*)(xb8 + ofs.x + co);
            uint4 r01 = *(const uint4*)(xb8 + ofs.y + co);
            uint4 r10 = *(const uint4*)(xb8 + ofs.z + co);
            uint4 r11 = *(const uint4*)(xb8 + ofs.w + co);
            const u32* q00 = (const u32*)&r00;
            const u32* q01 = (const u32*)&r01;
            const u32* q10 = (const u32*)&r10;
            const u32* q11 = (const u32*)&r11;
            u32 bw[4];
#pragma unroll
            for (int q = 0; q < 4; ++q) {
                float slo = bflo(q00[q]) * wt.x;
                slo = fmaf(bflo(q01[q]), wt.y, slo);
                slo = fmaf(bflo(q10[q]), wt.z, slo);
                slo = fmaf(bflo(q11[q]), wt.w, slo);
                float shi = bfhi(q00[q]) * wt.x;
                shi = fmaf(bfhi(q01[q]), wt.y, shi);
                shi = fmaf(bfhi(q10[q]), wt.z, shi);
                shi = fmaf(bfhi(q11[q]), wt.w, shi);
                bw[q] = cvt_pk_bf16(slo, shi);
            }
            short8 bfr;
            __builtin_memcpy(&bfr, bw, 16);
            int ks = (tap << 1) + k2;
            short8 a0 = ((const short8*)Wb)[(0 * 18 + ks) * 64 + lane];
            short8 a1 = ((const short8*)Wb)[(1 * 18 + ks) * 64 + lane];
            short8 a2 = ((const short8*)Wb)[(2 * 18 + ks) * 64 + lane];
            short8 a3 = ((const short8*)Wb)[(3 * 18 + ks) * 64 + lane];
            acc0 = __builtin_amdgcn_mfma_f32_16x16x32_bf16(a0, bfr, acc0, 0, 0, 0);
            acc1 = __builtin_amdgcn_mfma_f32_16x16x32_bf16(a1, bfr, acc1, 0, 0, 0);
            acc2 = __builtin_amdgcn_mfma_f32_16x16x32_bf16(a2, bfr, acc2, 0, 0, 0);
            acc3 = __builtin_amdgcn_mfma_f32_16x16x32_bf16(a3, bfr, acc3, 0, 0, 0);
        }
    }

    // ---- epilogue: D-frags -> out (o = otile*16 + hi*4 + r) ----
    float* op = out + ((size_t)lb << 20) + pix0 + mypix;
#pragma unroll
    for (int r = 0; r < 4; ++r) {
        op[(size_t)(0 * 16 + (hi << 2) + r) << 14] = acc0[r];
        op[(size_t)(1 * 16 + (hi << 2) + r) << 14] = acc1[r];
        op[(size_t)(2 * 16 + (hi << 2) + r) << 14] = acc2[r];
        op[(size_t)(3 * 16 + (hi << 2) + r) << 14] = acc3[r];
    }
}

// -------------------------------------------------------------------------
extern "C" void kernel_launch(void* const* d_in, const int* in_sizes, int n_in,
                              void* d_out, int out_size, void* d_ws, size_t ws_size,
                              hipStream_t stream)
{
    const float* x        = (const float*)d_in[0];
    const float* offset_w = (const float*)d_in[1];
    const float* offset_b = (const float*)d_in[2];
    const float* mod_w    = (const float*)d_in[3];
    const float* mod_b    = (const float*)d_in[4];
    const float* weight   = (const float*)d_in[5];
    float* out = (float*)d_out;

    // Workspace (u16), total ~8.1 MiB:
    //   Wb : 36864 | OWb : 18432 | xt : 4 batches * HW * C = 4,194,304
    u16* Wb  = (u16*)d_ws;
    u16* OWb = Wb + 36864;
    u16* xt  = OWb + 18432;

    repack<<<216, 256, 0, stream>>>(weight, offset_w, mod_w, Wb, OWb);
    prep_t<<<1024, 256, 0, stream>>>(x, xt);
    fused_dcn<<<2048, 128, 0, stream>>>(xt, Wb, OWb, offset_b, mod_b, out);
}